// Round 16
// baseline (430.205 us; speedup 1.0000x reference)
//
#include <hip/hip_runtime.h>
#include <hip/hip_fp16.h>

// out[n,:] = ci[n] * sum_{e: dst[e]==n} sigmoid(<review_feat[e,:], ps_w>) * cj[src[e]] * weight[src[e],:]
//
// Round-15 lesson: NT loads broke L3 absorption of the review stream (~half
// of the 819MB was L3-hit across graph replays; NT forced it all to HBM,
// +60us). Round 16 = round 15 with NT REVERTED (plain loads/stores), keeping
// the k3-scan-merged-into-kM structure. Clean bisection of the two r14 ideas.
// Pipeline: kZ zero | kM (hist -> scan || gate-stream) | k4W wcj||scatter | k5

#define SCAN_TILE    2048          // elems per scan tile (8/thread @ 256 thr)
#define HIST_BLOCKS  256
#define GATE_BLOCKS  2048
#define WCJ_BLOCKS   512

// ---------------- kZ: zero deg + barrier counters ----------------
__global__ __launch_bounds__(256) void kZ_zero(
    unsigned* __restrict__ deg, unsigned* __restrict__ done1,
    unsigned* __restrict__ done2, int n)
{
    const int i = blockIdx.x * 256 + threadIdx.x;
    if (i < n) deg[i] = 0u;
    if (i == 0) { *done1 = 0u; *done2 = 0u; }
}

// ---------------- kM: hist+rank -> scan (blocks 0..255) || gate stream ----------------
__global__ __launch_bounds__(256) void kM_hist_scan_gate(
    const float* __restrict__ review_feat,  // [E,64]
    const float* __restrict__ ps_w,         // [64]
    const int*   __restrict__ dst,          // [E]
    float*       __restrict__ scale,        // [E] out: sigmoid(dot)
    unsigned*    __restrict__ rank,         // [E] out
    unsigned*    __restrict__ deg,          // [N] (pre-zeroed)
    unsigned*    __restrict__ offs,         // [N+1] out
    unsigned*    __restrict__ tileagg,      // [ntiles]
    unsigned*    __restrict__ done1,        // [1] hist barrier (pre-zeroed)
    unsigned*    __restrict__ done2,        // [1] agg barrier  (pre-zeroed)
    int E, int N, int ntiles)
{
    __shared__ unsigned lds[SCAN_TILE];
    __shared__ unsigned sums[256];
    __shared__ unsigned sh_prefix;

    if (blockIdx.x < HIST_BLOCKS) {
        // ---- latency lane: histogram + rank, 4-deep batches ----
        {
            const long long gsz = (long long)HIST_BLOCKS * 256;
            const long long t0  = (long long)blockIdx.x * 256 + threadIdx.x;
            for (long long b = t0; b < E; b += gsz * 4) {
                long long e[4];
                int d[4];
                #pragma unroll
                for (int u = 0; u < 4; ++u) {
                    e[u] = b + u * gsz;
                    d[u] = (e[u] < E) ? dst[e[u]] : 0;
                }
                unsigned r[4];
                #pragma unroll
                for (int u = 0; u < 4; ++u)
                    if (e[u] < E) r[u] = atomicAdd(&deg[d[u]], 1u);
                #pragma unroll
                for (int u = 0; u < 4; ++u)
                    if (e[u] < E) rank[e[u]] = r[u];
            }
        }
        __syncthreads();
        __threadfence();
        if (threadIdx.x == 0) atomicAdd(done1, 1u);
        if (blockIdx.x >= (unsigned)ntiles) return;

        // ---- wait until ALL hist blocks have finished ----
        if (threadIdx.x == 0) {
            while (atomicAdd(done1, 0u) < (unsigned)HIST_BLOCKS) { }
        }
        __syncthreads();

        // ---- tile scan (block b handles tile b) ----
        const int t = threadIdx.x;
        const int b = blockIdx.x;
        const int base = b * SCAN_TILE;
        #pragma unroll
        for (int i = 0; i < SCAN_TILE / 256; ++i) {
            const int idx = base + t + i * 256;
            lds[t + i * 256] = (idx < N) ? deg[idx] : 0u;   // coalesced
        }
        __syncthreads();
        unsigned v[SCAN_TILE / 256];
        unsigned s = 0;
        #pragma unroll
        for (int i = 0; i < SCAN_TILE / 256; ++i) {
            v[i] = lds[(SCAN_TILE / 256) * t + i];
            s += v[i];
        }
        sums[t] = s;
        __syncthreads();
        for (int off = 1; off < 256; off <<= 1) {   // Hillis-Steele
            const unsigned x = (t >= off) ? sums[t - off] : 0u;
            __syncthreads();
            sums[t] += x;
            __syncthreads();
        }
        unsigned run = sums[t] - s;
        #pragma unroll
        for (int i = 0; i < SCAN_TILE / 256; ++i) {
            lds[(SCAN_TILE / 256) * t + i] = run;
            run += v[i];
        }
        __syncthreads();

        const unsigned agg = sums[255];
        if (t == 0) {
            atomicExch(&tileagg[b], agg);
            __threadfence();
            atomicAdd(done2, 1u);
            while (atomicAdd(done2, 0u) < (unsigned)ntiles) { }
            unsigned p = 0;
            for (int i = 0; i < b; ++i) p += atomicAdd(&tileagg[i], 0u);
            sh_prefix = p;
            if (b == ntiles - 1) offs[N] = p + agg;   // == E
        }
        __syncthreads();

        const unsigned pfx = sh_prefix;
        #pragma unroll
        for (int i = 0; i < SCAN_TILE / 256; ++i) {
            const int idx = base + t + i * 256;
            if (idx < N) offs[idx] = lds[t + i * 256] + pfx;
        }
        return;
    }

    // ---- BW lane: PURE gate stream (plain loads; L3 absorbs ~half) ----
    const int bid   = blockIdx.x - HIST_BLOCKS;
    const int lane  = threadIdx.x & 63;
    const int wib   = threadIdx.x >> 6;
    const int group = lane >> 4;
    const int sub   = lane & 15;
    const float4 pw = *reinterpret_cast<const float4*>(ps_w + sub * 4);

    const long long nwaves = (long long)GATE_BLOCKS * 4;
    for (long long w = (long long)bid * 4 + wib; w * 16 < E; w += nwaves) {
        const long long ebase = w * 16;
        float4 rv[4];
        #pragma unroll
        for (int u = 0; u < 4; ++u) {
            const long long e = ebase + u * 4 + group;
            rv[u] = (e < E) ? *reinterpret_cast<const float4*>(review_feat + e * 64 + sub * 4)
                            : make_float4(0.f, 0.f, 0.f, 0.f);
        }
        float x[4];
        #pragma unroll
        for (int u = 0; u < 4; ++u) {
            float t = rv[u].x * pw.x + rv[u].y * pw.y + rv[u].z * pw.z + rv[u].w * pw.w;
            t += __shfl_xor(t, 1);
            t += __shfl_xor(t, 2);
            t += __shfl_xor(t, 4);
            t += __shfl_xor(t, 8);
            x[u] = t;
        }
        if (sub == 0) {
            #pragma unroll
            for (int u = 0; u < 4; ++u) {
                const long long e = ebase + u * 4 + group;
                if (e < E) scale[e] = 1.f / (1.f + __expf(-x[u]));
            }
        }
    }
}

// ---------------- k4W: wcj(fp16) precompute || pure scatter ----------------
__global__ __launch_bounds__(256) void k4_scatter_wcj(
    const int*      __restrict__ src,
    const int*      __restrict__ dst,
    const float*    __restrict__ scale,
    const unsigned* __restrict__ rank,
    const unsigned* __restrict__ offs,
    int2*           __restrict__ pairs,
    const float*    __restrict__ weight,   // [N,64]
    const float*    __restrict__ cj,       // [N]
    __half*         __restrict__ wcj,      // [N,64] out (fp16)
    int E, int N)
{
    if (blockIdx.x < WCJ_BLOCKS) {
        // ---- BW lane: wcj = fp16(weight * cj), 8 halves (16B out) per iter ----
        const long long tid = (long long)blockIdx.x * 256 + threadIdx.x;
        const long long nthreads = (long long)WCJ_BLOCKS * 256;
        const long long nq = (long long)N * 8;   // units of 8 elements
        for (long long i = tid; i < nq; i += nthreads) {
            const int n = (int)(i >> 3);
            const float4 w0 = reinterpret_cast<const float4*>(weight)[i * 2];
            const float4 w1 = reinterpret_cast<const float4*>(weight)[i * 2 + 1];
            const float c = cj[n];
            const unsigned r0 = (unsigned)__half_as_ushort(__float2half(w0.x * c))
                              | ((unsigned)__half_as_ushort(__float2half(w0.y * c)) << 16);
            const unsigned r1 = (unsigned)__half_as_ushort(__float2half(w0.z * c))
                              | ((unsigned)__half_as_ushort(__float2half(w0.w * c)) << 16);
            const unsigned r2 = (unsigned)__half_as_ushort(__float2half(w1.x * c))
                              | ((unsigned)__half_as_ushort(__float2half(w1.y * c)) << 16);
            const unsigned r3 = (unsigned)__half_as_ushort(__float2half(w1.z * c))
                              | ((unsigned)__half_as_ushort(__float2half(w1.w * c)) << 16);
            reinterpret_cast<uint4*>(wcj)[i] = make_uint4(r0, r1, r2, r3);
        }
        return;
    }

    // ---- latency lane: pure scatter, 8-deep ILP ----
    const long long gsz = (long long)(gridDim.x - WCJ_BLOCKS) * 256;
    const long long t0  = (long long)(blockIdx.x - WCJ_BLOCKS) * 256 + threadIdx.x;

    long long e[8];
    int s[8], d[8];
    float sc[8];
    unsigned r[8];
    #pragma unroll
    for (int u = 0; u < 8; ++u) {
        e[u] = t0 + u * gsz;
        const bool ok = e[u] < E;
        s[u]  = ok ? src[e[u]]   : 0;
        d[u]  = ok ? dst[e[u]]   : 0;
        sc[u] = ok ? scale[e[u]] : 0.f;
        r[u]  = ok ? rank[e[u]]  : 0u;
    }
    unsigned o[8];
    #pragma unroll
    for (int u = 0; u < 8; ++u)
        o[u] = (e[u] < E) ? offs[d[u]] : 0u;
    #pragma unroll
    for (int u = 0; u < 8; ++u)
        if (e[u] < E) pairs[o[u] + r[u]] = make_int2(s[u], __float_as_int(sc[u]));
}

// ---------------- k5: gather-reduce from fp16 wcj, xci epilogue ----------------
__global__ __launch_bounds__(256, 4) void k5_gather(
    const __half*   __restrict__ wcj,     // [N,64] fp16 = weight*cj
    const float*    __restrict__ ci,      // [N]
    const unsigned* __restrict__ offs,    // [N+1]
    const int2*     __restrict__ pairs,   // [E]
    float*          __restrict__ out,     // [N,64]
    int N)
{
    const int lane  = threadIdx.x & 63;
    const int wib   = threadIdx.x >> 6;
    const int group = lane >> 4;   // node within wave
    const int sub   = lane & 15;   // 4-elem chunk of the row

    const long long n = ((long long)blockIdx.x * 4 + wib) * 4 + group;
    const bool valid = (n < N);

    unsigned start = 0, cnt = 0;
    if (valid) { start = offs[n]; cnt = offs[n + 1] - start; }

    int2 p = make_int2(0, 0);
    if (sub < cnt) p = pairs[start + sub];

    float4 acc = make_float4(0.f, 0.f, 0.f, 0.f);
    for (unsigned k0 = 0; __any((int)(k0 < cnt)); k0 += 16) {
        int2 pn = make_int2(0, 0);
        const unsigned nk = k0 + 16;
        if (nk + sub < cnt) pn = pairs[start + nk + sub];

        int m = (int)cnt - (int)k0;
        if (m > 16) m = 16;
        #pragma unroll 8
        for (int j = 0; j < m; ++j) {
            const int   s  = __shfl(p.x, (group << 4) + j);
            const float sc = __int_as_float(__shfl(p.y, (group << 4) + j));
            const uint2 raw = *reinterpret_cast<const uint2*>(
                wcj + (long long)s * 64 + sub * 4);
            acc.x += sc * __half2float(__ushort_as_half((unsigned short)(raw.x & 0xffffu)));
            acc.y += sc * __half2float(__ushort_as_half((unsigned short)(raw.x >> 16)));
            acc.z += sc * __half2float(__ushort_as_half((unsigned short)(raw.y & 0xffffu)));
            acc.w += sc * __half2float(__ushort_as_half((unsigned short)(raw.y >> 16)));
        }
        p = pn;
    }
    if (valid) {
        const float c = ci[n];
        *reinterpret_cast<float4*>(out + n * 64 + sub * 4) =
            make_float4(acc.x * c, acc.y * c, acc.z * c, acc.w * c);
    }
}

extern "C" void kernel_launch(void* const* d_in, const int* in_sizes, int n_in,
                              void* d_out, int out_size, void* d_ws, size_t ws_size,
                              hipStream_t stream) {
    const float* weight      = (const float*)d_in[0];
    const float* ps_w        = (const float*)d_in[1];
    const float* review_feat = (const float*)d_in[2];
    const float* cj          = (const float*)d_in[3];
    const float* ci          = (const float*)d_in[4];
    const int*   src         = (const int*)d_in[5];
    const int*   dst         = (const int*)d_in[6];
    float*       out         = (float*)d_out;

    const int N = in_sizes[3];
    const int E = in_sizes[5];
    const int ntiles = (N + SCAN_TILE - 1) / SCAN_TILE;   // 49 <= HIST_BLOCKS

    size_t off = 0;
    auto take = [&](size_t bytes) { size_t o = off; off = (off + bytes + 255) & ~(size_t)255; return o; };
    const size_t pairs_o   = take((size_t)E * 8);
    const size_t scale_o   = take((size_t)E * 4);
    const size_t rank_o    = take((size_t)E * 4);
    const size_t wcj_o     = take((size_t)N * 64 * 2);   // fp16
    const size_t deg_o     = take((size_t)N * 4);
    const size_t offs_o    = take(((size_t)N + 1) * 4);
    const size_t tileagg_o = take((size_t)ntiles * 4);
    const size_t done1_o   = take(4);
    const size_t done2_o   = take(4);

    char* base = (char*)d_ws;
    int2*     pairs   = (int2*)    (base + pairs_o);
    float*    scale   = (float*)   (base + scale_o);
    unsigned* rank    = (unsigned*)(base + rank_o);
    __half*   wcj     = (__half*)  (base + wcj_o);
    unsigned* deg     = (unsigned*)(base + deg_o);
    unsigned* offs    = (unsigned*)(base + offs_o);
    unsigned* tileagg = (unsigned*)(base + tileagg_o);
    unsigned* done1   = (unsigned*)(base + done1_o);
    unsigned* done2   = (unsigned*)(base + done2_o);

    kZ_zero<<<(N + 255) / 256, 256, 0, stream>>>(deg, done1, done2, N);
    kM_hist_scan_gate<<<HIST_BLOCKS + GATE_BLOCKS, 256, 0, stream>>>(
        review_feat, ps_w, dst, scale, rank, deg, offs, tileagg, done1, done2,
        E, N, ntiles);
    const int scatterBlocks = (int)(((long long)E + 8LL * 256 - 1) / (8LL * 256));
    k4_scatter_wcj<<<WCJ_BLOCKS + scatterBlocks, 256, 0, stream>>>(
        src, dst, scale, rank, offs, pairs, weight, cj, wcj, E, N);
    const int blocksD = (N + 15) / 16;   // 16 nodes per block (4 waves x 4 nodes)
    k5_gather<<<blocksD, 256, 0, stream>>>(wcj, ci, offs, pairs, out, N);
}

// Round 17
// 380.298 us; speedup vs baseline: 1.1312x; 1.1312x over previous
//
#include <hip/hip_runtime.h>
#include <hip/hip_fp16.h>

// out[n,:] = ci[n] * sum_{e: dst[e]==n} sigmoid(<review_feat[e,:], ps_w>) * cj[src[e]] * weight[src[e],:]
//
// Round-16 bisection: the in-kM spin-barrier scan merge cost +45us (NT was
// ~neutral). REVERT to round-13's proven 5-dispatch pipeline; single change:
// gate stream now processes 32 edges/wave-iter (8 independent 1KB loads in
// flight, was 4) -- r8 profile showed VALUBusy 28% => stream is MLP-limited.
// Pipeline: kZ zero | kM hist||gate | k3 scan | k4W wcj||scatter | k5 gather

#define SCAN_TILE    2048
#define SCAN_THREADS 512
#define HIST_BLOCKS  256
#define GATE_BLOCKS  2048
#define WCJ_BLOCKS   512

// ---------------- kZ: zero deg + done ----------------
__global__ __launch_bounds__(256) void kZ_zero(
    unsigned* __restrict__ deg, unsigned* __restrict__ done, int n)
{
    const int i = blockIdx.x * 256 + threadIdx.x;
    if (i < n) deg[i] = 0u;
    if (i == 0) *done = 0u;
}

// ---------------- kM: merged hist+rank || pure gate stream (8-deep MLP) ----------------
__global__ __launch_bounds__(256) void kM_hist_gate(
    const float* __restrict__ review_feat,  // [E,64]
    const float* __restrict__ ps_w,         // [64]
    const int*   __restrict__ dst,          // [E]
    float*       __restrict__ scale,        // [E] out: sigmoid(dot)
    unsigned*    __restrict__ rank,         // [E] out
    unsigned*    __restrict__ deg,          // [N] (pre-zeroed)
    int E)
{
    if (blockIdx.x < HIST_BLOCKS) {
        // ---- latency lane: histogram + rank, 4-deep batches ----
        const long long gsz = (long long)HIST_BLOCKS * 256;
        const long long t0  = (long long)blockIdx.x * 256 + threadIdx.x;
        for (long long b = t0; b < E; b += gsz * 4) {
            long long e[4];
            int d[4];
            #pragma unroll
            for (int u = 0; u < 4; ++u) {
                e[u] = b + u * gsz;
                d[u] = (e[u] < E) ? dst[e[u]] : 0;
            }
            unsigned r[4];
            #pragma unroll
            for (int u = 0; u < 4; ++u)
                if (e[u] < E) r[u] = atomicAdd(&deg[d[u]], 1u);
            #pragma unroll
            for (int u = 0; u < 4; ++u)
                if (e[u] < E) rank[e[u]] = r[u];
        }
        return;
    }

    // ---- BW lane: PURE gate stream, 32 edges/wave-iter (8 loads in flight) ----
    const int bid   = blockIdx.x - HIST_BLOCKS;
    const int lane  = threadIdx.x & 63;
    const int wib   = threadIdx.x >> 6;
    const int group = lane >> 4;
    const int sub   = lane & 15;
    const float4 pw = *reinterpret_cast<const float4*>(ps_w + sub * 4);

    const long long nwaves = (long long)GATE_BLOCKS * 4;
    for (long long w = (long long)bid * 4 + wib; w * 32 < E; w += nwaves) {
        const long long ebase = w * 32;
        float4 rv[8];
        #pragma unroll
        for (int u = 0; u < 8; ++u) {
            const long long e = ebase + u * 4 + group;
            rv[u] = (e < E) ? *reinterpret_cast<const float4*>(review_feat + e * 64 + sub * 4)
                            : make_float4(0.f, 0.f, 0.f, 0.f);
        }
        float x[8];
        #pragma unroll
        for (int u = 0; u < 8; ++u) {
            float t = rv[u].x * pw.x + rv[u].y * pw.y + rv[u].z * pw.z + rv[u].w * pw.w;
            t += __shfl_xor(t, 1);
            t += __shfl_xor(t, 2);
            t += __shfl_xor(t, 4);
            t += __shfl_xor(t, 8);
            x[u] = t;
        }
        if (sub == 0) {
            #pragma unroll
            for (int u = 0; u < 8; ++u) {
                const long long e = ebase + u * 4 + group;
                if (e < E) scale[e] = 1.f / (1.f + __expf(-x[u]));
            }
        }
    }
}

// ---------------- k3: one-dispatch exclusive scan (offs only) ----------------
__global__ __launch_bounds__(SCAN_THREADS) void k3_scan_onepass(
    const unsigned* __restrict__ deg,      // [N]
    unsigned*       __restrict__ offs,     // [N+1]
    unsigned*       __restrict__ tileagg,  // [ntiles]
    unsigned*       __restrict__ done,     // [1] (pre-zeroed)
    int N, int ntiles)
{
    __shared__ unsigned lds[SCAN_TILE];
    __shared__ unsigned sums[SCAN_THREADS];
    __shared__ unsigned sh_prefix;
    const int t = threadIdx.x;
    const int b = blockIdx.x;
    const int base = b * SCAN_TILE;

    #pragma unroll
    for (int i = 0; i < SCAN_TILE / SCAN_THREADS; ++i) {
        const int idx = base + t + i * SCAN_THREADS;
        lds[t + i * SCAN_THREADS] = (idx < N) ? deg[idx] : 0u;   // coalesced
    }
    __syncthreads();

    unsigned v[SCAN_TILE / SCAN_THREADS];
    unsigned s = 0;
    #pragma unroll
    for (int i = 0; i < SCAN_TILE / SCAN_THREADS; ++i) {
        v[i] = lds[(SCAN_TILE / SCAN_THREADS) * t + i];
        s += v[i];
    }
    sums[t] = s;
    __syncthreads();
    for (int off = 1; off < SCAN_THREADS; off <<= 1) {   // Hillis-Steele
        const unsigned x = (t >= off) ? sums[t - off] : 0u;
        __syncthreads();
        sums[t] += x;
        __syncthreads();
    }
    unsigned run = sums[t] - s;
    #pragma unroll
    for (int i = 0; i < SCAN_TILE / SCAN_THREADS; ++i) {
        lds[(SCAN_TILE / SCAN_THREADS) * t + i] = run;
        run += v[i];
    }
    __syncthreads();

    const unsigned agg = sums[SCAN_THREADS - 1];
    if (t == 0) {
        atomicExch(&tileagg[b], agg);
        __threadfence();
        atomicAdd(done, 1u);
        while (atomicAdd(done, 0u) < (unsigned)ntiles) { }
        unsigned p = 0;
        for (int i = 0; i < b; ++i) p += atomicAdd(&tileagg[i], 0u);
        sh_prefix = p;
        if (b == ntiles - 1) offs[N] = p + agg;   // == E
    }
    __syncthreads();

    const unsigned pfx = sh_prefix;
    #pragma unroll
    for (int i = 0; i < SCAN_TILE / SCAN_THREADS; ++i) {
        const int idx = base + t + i * SCAN_THREADS;
        if (idx < N) offs[idx] = lds[t + i * SCAN_THREADS] + pfx;
    }
}

// ---------------- k4W: wcj(fp16) precompute || pure scatter ----------------
__global__ __launch_bounds__(256) void k4_scatter_wcj(
    const int*      __restrict__ src,
    const int*      __restrict__ dst,
    const float*    __restrict__ scale,
    const unsigned* __restrict__ rank,
    const unsigned* __restrict__ offs,
    int2*           __restrict__ pairs,
    const float*    __restrict__ weight,   // [N,64]
    const float*    __restrict__ cj,       // [N]
    __half*         __restrict__ wcj,      // [N,64] out (fp16)
    int E, int N)
{
    if (blockIdx.x < WCJ_BLOCKS) {
        // ---- BW lane: wcj = fp16(weight * cj), 8 halves (16B out) per iter ----
        const long long tid = (long long)blockIdx.x * 256 + threadIdx.x;
        const long long nthreads = (long long)WCJ_BLOCKS * 256;
        const long long nq = (long long)N * 8;   // units of 8 elements
        for (long long i = tid; i < nq; i += nthreads) {
            const int n = (int)(i >> 3);
            const float4 w0 = reinterpret_cast<const float4*>(weight)[i * 2];
            const float4 w1 = reinterpret_cast<const float4*>(weight)[i * 2 + 1];
            const float c = cj[n];
            const unsigned r0 = (unsigned)__half_as_ushort(__float2half(w0.x * c))
                              | ((unsigned)__half_as_ushort(__float2half(w0.y * c)) << 16);
            const unsigned r1 = (unsigned)__half_as_ushort(__float2half(w0.z * c))
                              | ((unsigned)__half_as_ushort(__float2half(w0.w * c)) << 16);
            const unsigned r2 = (unsigned)__half_as_ushort(__float2half(w1.x * c))
                              | ((unsigned)__half_as_ushort(__float2half(w1.y * c)) << 16);
            const unsigned r3 = (unsigned)__half_as_ushort(__float2half(w1.z * c))
                              | ((unsigned)__half_as_ushort(__float2half(w1.w * c)) << 16);
            reinterpret_cast<uint4*>(wcj)[i] = make_uint4(r0, r1, r2, r3);
        }
        return;
    }

    // ---- latency lane: pure scatter, 8-deep ILP ----
    const long long gsz = (long long)(gridDim.x - WCJ_BLOCKS) * 256;
    const long long t0  = (long long)(blockIdx.x - WCJ_BLOCKS) * 256 + threadIdx.x;

    long long e[8];
    int s[8], d[8];
    float sc[8];
    unsigned r[8];
    #pragma unroll
    for (int u = 0; u < 8; ++u) {
        e[u] = t0 + u * gsz;
        const bool ok = e[u] < E;
        s[u]  = ok ? src[e[u]]   : 0;
        d[u]  = ok ? dst[e[u]]   : 0;
        sc[u] = ok ? scale[e[u]] : 0.f;
        r[u]  = ok ? rank[e[u]]  : 0u;
    }
    unsigned o[8];
    #pragma unroll
    for (int u = 0; u < 8; ++u)
        o[u] = (e[u] < E) ? offs[d[u]] : 0u;
    #pragma unroll
    for (int u = 0; u < 8; ++u)
        if (e[u] < E) pairs[o[u] + r[u]] = make_int2(s[u], __float_as_int(sc[u]));
}

// ---------------- k5: gather-reduce from fp16 wcj, xci epilogue ----------------
__global__ __launch_bounds__(256, 4) void k5_gather(
    const __half*   __restrict__ wcj,     // [N,64] fp16 = weight*cj
    const float*    __restrict__ ci,      // [N]
    const unsigned* __restrict__ offs,    // [N+1]
    const int2*     __restrict__ pairs,   // [E]
    float*          __restrict__ out,     // [N,64]
    int N)
{
    const int lane  = threadIdx.x & 63;
    const int wib   = threadIdx.x >> 6;
    const int group = lane >> 4;   // node within wave
    const int sub   = lane & 15;   // 4-elem chunk of the row

    const long long n = ((long long)blockIdx.x * 4 + wib) * 4 + group;
    const bool valid = (n < N);

    unsigned start = 0, cnt = 0;
    if (valid) { start = offs[n]; cnt = offs[n + 1] - start; }

    int2 p = make_int2(0, 0);
    if (sub < cnt) p = pairs[start + sub];

    float4 acc = make_float4(0.f, 0.f, 0.f, 0.f);
    for (unsigned k0 = 0; __any((int)(k0 < cnt)); k0 += 16) {
        int2 pn = make_int2(0, 0);
        const unsigned nk = k0 + 16;
        if (nk + sub < cnt) pn = pairs[start + nk + sub];

        int m = (int)cnt - (int)k0;
        if (m > 16) m = 16;
        #pragma unroll 8
        for (int j = 0; j < m; ++j) {
            const int   s  = __shfl(p.x, (group << 4) + j);
            const float sc = __int_as_float(__shfl(p.y, (group << 4) + j));
            const uint2 raw = *reinterpret_cast<const uint2*>(
                wcj + (long long)s * 64 + sub * 4);
            acc.x += sc * __half2float(__ushort_as_half((unsigned short)(raw.x & 0xffffu)));
            acc.y += sc * __half2float(__ushort_as_half((unsigned short)(raw.x >> 16)));
            acc.z += sc * __half2float(__ushort_as_half((unsigned short)(raw.y & 0xffffu)));
            acc.w += sc * __half2float(__ushort_as_half((unsigned short)(raw.y >> 16)));
        }
        p = pn;
    }
    if (valid) {
        const float c = ci[n];
        *reinterpret_cast<float4*>(out + n * 64 + sub * 4) =
            make_float4(acc.x * c, acc.y * c, acc.z * c, acc.w * c);
    }
}

extern "C" void kernel_launch(void* const* d_in, const int* in_sizes, int n_in,
                              void* d_out, int out_size, void* d_ws, size_t ws_size,
                              hipStream_t stream) {
    const float* weight      = (const float*)d_in[0];
    const float* ps_w        = (const float*)d_in[1];
    const float* review_feat = (const float*)d_in[2];
    const float* cj          = (const float*)d_in[3];
    const float* ci          = (const float*)d_in[4];
    const int*   src         = (const int*)d_in[5];
    const int*   dst         = (const int*)d_in[6];
    float*       out         = (float*)d_out;

    const int N = in_sizes[3];
    const int E = in_sizes[5];
    const int ntiles = (N + SCAN_TILE - 1) / SCAN_TILE;

    size_t off = 0;
    auto take = [&](size_t bytes) { size_t o = off; off = (off + bytes + 255) & ~(size_t)255; return o; };
    const size_t pairs_o   = take((size_t)E * 8);
    const size_t scale_o   = take((size_t)E * 4);
    const size_t rank_o    = take((size_t)E * 4);
    const size_t wcj_o     = take((size_t)N * 64 * 2);   // fp16
    const size_t deg_o     = take((size_t)N * 4);
    const size_t offs_o    = take(((size_t)N + 1) * 4);
    const size_t tileagg_o = take((size_t)ntiles * 4);
    const size_t done_o    = take(4);

    char* base = (char*)d_ws;
    int2*     pairs   = (int2*)    (base + pairs_o);
    float*    scale   = (float*)   (base + scale_o);
    unsigned* rank    = (unsigned*)(base + rank_o);
    __half*   wcj     = (__half*)  (base + wcj_o);
    unsigned* deg     = (unsigned*)(base + deg_o);
    unsigned* offs    = (unsigned*)(base + offs_o);
    unsigned* tileagg = (unsigned*)(base + tileagg_o);
    unsigned* done    = (unsigned*)(base + done_o);

    kZ_zero<<<(N + 255) / 256, 256, 0, stream>>>(deg, done, N);
    kM_hist_gate<<<HIST_BLOCKS + GATE_BLOCKS, 256, 0, stream>>>(
        review_feat, ps_w, dst, scale, rank, deg, E);
    k3_scan_onepass<<<ntiles, SCAN_THREADS, 0, stream>>>(deg, offs, tileagg, done,
                                                         N, ntiles);
    const int scatterBlocks = (int)(((long long)E + 8LL * 256 - 1) / (8LL * 256));
    k4_scatter_wcj<<<WCJ_BLOCKS + scatterBlocks, 256, 0, stream>>>(
        src, dst, scale, rank, offs, pairs, weight, cj, wcj, E, N);
    const int blocksD = (N + 15) / 16;   // 16 nodes per block (4 waves x 4 nodes)
    k5_gather<<<blocksD, 256, 0, stream>>>(wcj, ci, offs, pairs, out, N);
}